// Round 1
// baseline (76.067 us; speedup 1.0000x reference)
//
#include <hip/hip_runtime.h>
#include <math.h>

// Problem constants (fixed by setup_inputs / module constants)
#define BS   4
#define HDIM 256
#define WDIM 256
#define HW   65536          // HDIM*WDIM
#define GMAX 500
#define K_OFF 120           // 8*(1+2+3+4+5)
#define DIS_THR 20.0f       // STRIDE*RADIUS

// ---------------------------------------------------------------------------
// Kernel 1: pixels_out + negative flag
//   pixels[n] = (n>>8, n&255)  (exact: meshgrid(arange(w),arange(h),'ij'))
//   flag[b,n] = -1 if min over valid g of dist(pixel, gt) > 20 else 0
// Reference rounding replicated: d2 = (p2 + g2) - 2*cross, no FMA contraction,
// dist = sqrtf(max(d2,0)), strict '>' comparison.
// ---------------------------------------------------------------------------
__global__ __launch_bounds__(256) void pix_flag_kernel(
    const float* __restrict__ gt_points,   // (BS, GMAX, 2)
    const int*   __restrict__ gt_nums,     // (BS,)
    float*       __restrict__ out)         // [BS*HW*2 pixels | BS*HW flag]
{
    const int b = blockIdx.y;
    const int n = blockIdx.x * 256 + threadIdx.x;

    __shared__ float sgx[GMAX];
    __shared__ float sgy[GMAX];
    __shared__ float sg2[GMAX];

    const int num = gt_nums[b];

    for (int g = threadIdx.x; g < num; g += 256) {
        float gx = gt_points[(b * GMAX + g) * 2 + 0];
        float gy = gt_points[(b * GMAX + g) * 2 + 1];
        sgx[g] = gx;
        sgy[g] = gy;
        // g2 = gx*gx + gy*gy, each op rounded separately (matches np/XLA elementwise)
        sg2[g] = __fadd_rn(__fmul_rn(gx, gx), __fmul_rn(gy, gy));
    }
    __syncthreads();

    const float px = (float)(n >> 8);    // n / HDIM
    const float py = (float)(n & 255);   // n % HDIM
    // p2 exact (integer-valued, <= 130050 < 2^24)
    const float p2 = px * px + py * py;

    bool found = false;
    for (int g = 0; g < num; ++g) {
        float cx = __fmul_rn(px, sgx[g]);
        float cy = __fmul_rn(py, sgy[g]);
        float cross = __fadd_rn(cx, cy);
        float d2 = __fsub_rn(__fadd_rn(p2, sg2[g]), __fmul_rn(2.0f, cross));
        float dist = sqrtf(fmaxf(d2, 0.0f));
        if (dist <= DIS_THR) { found = true; break; }
    }

    // pixels_out: (BS, HW, 2) — vectorized 8B store
    float2* pout = (float2*)out;
    pout[b * HW + n] = make_float2(px, py);

    // flag: offset BS*HW*2
    out[BS * HW * 2 + b * HW + n] = found ? 0.0f : -1.0f;
}

// ---------------------------------------------------------------------------
// Kernel 2: positive scatter — flag[b, base+off] = 1.0 for valid g, in-range idx
// Ring offsets computed per-thread in double (matches np float64 trig + np.round
// half-even). base = rintf(gx*256 + gy*256) — products exact, one rounded add.
// ---------------------------------------------------------------------------
__global__ __launch_bounds__(128) void scatter_kernel(
    const float* __restrict__ gt_points,
    const int*   __restrict__ gt_nums,
    float*       __restrict__ out)
{
    const int b = blockIdx.y;
    const int g = blockIdx.x;
    if (g >= gt_nums[b]) return;

    const int k = threadIdx.x;
    if (k >= K_OFF) return;

    // ring index from cumulative sizes {8,16,24,32,40} -> starts {0,8,24,48,80}
    int i, start;
    if      (k < 8)  { i = 0; start = 0;  }
    else if (k < 24) { i = 1; start = 8;  }
    else if (k < 48) { i = 2; start = 24; }
    else if (k < 80) { i = 3; start = 48; }
    else             { i = 4; start = 80; }
    const int    j   = k - start;
    const int    nn  = 8 * (i + 1);
    const double r   = 4.0 * (i + 1);
    const double ang = ((double)j / (double)nn) * 6.283185307179586; // 2.0*np.pi
    const double dx  = r * cos(ang);
    const double dy  = r * sin(ang);
    const int off = (int)rint(dy * 256.0 + dx * 256.0);  // np.round, half-even

    const float gx = gt_points[(b * GMAX + g) * 2 + 0];
    const float gy = gt_points[(b * GMAX + g) * 2 + 1];
    // gx*256, gy*256 exact (power of 2); single rounded add; rintf = half-even
    const int base = (int)rintf(__fadd_rn(__fmul_rn(gx, 256.0f),
                                          __fmul_rn(gy, 256.0f)));
    const int idx = base + off;
    if (idx >= 0 && idx < HW)
        out[BS * HW * 2 + b * HW + idx] = 1.0f;
}

extern "C" void kernel_launch(void* const* d_in, const int* in_sizes, int n_in,
                              void* d_out, int out_size, void* d_ws, size_t ws_size,
                              hipStream_t stream) {
    // inputs: [0] images (unused, shapes are compile-time), [1] gt_points, [2] gt_nums
    const float* gt_points = (const float*)d_in[1];
    const int*   gt_nums   = (const int*)d_in[2];
    float* out = (float*)d_out;

    dim3 grid1(HW / 256, BS);
    pix_flag_kernel<<<grid1, 256, 0, stream>>>(gt_points, gt_nums, out);

    dim3 grid2(GMAX, BS);
    scatter_kernel<<<grid2, 128, 0, stream>>>(gt_points, gt_nums, out);
}

// Round 2
// 18.514 us; speedup vs baseline: 4.1087x; 4.1087x over previous
//
#include <hip/hip_runtime.h>
#include <math.h>

// Problem constants (fixed by setup_inputs / module constants)
#define BS   4
#define HDIM 256
#define WDIM 256
#define HW   65536          // HDIM*WDIM
#define GMAX 500
#define K_OFF 120           // 8*(1+2+3+4+5)
#define DIS_THR 20.0f       // STRIDE*RADIUS
#define FLAG_OFF (BS * HW * 2)

// ---------------------------------------------------------------------------
// Kernel A: pixels_out + flag = -1 everywhere.
//   pixels[b*HW+n] = (n>>8, n&255)   (meshgrid(arange(w),arange(h),'ij'))
// ---------------------------------------------------------------------------
__global__ __launch_bounds__(256) void init_kernel(float* __restrict__ out)
{
    const int t = blockIdx.x * 256 + threadIdx.x;   // 0 .. BS*HW-1
    const int n = t & (HW - 1);
    const float px = (float)(n >> 8);
    const float py = (float)(n & 255);
    ((float2*)out)[t] = make_float2(px, py);
    out[FLAG_OFF + t] = -1.0f;
}

// ---------------------------------------------------------------------------
// Kernel B: disk rasterization — for each valid GT point, write flag = 0.0 at
// every pixel with dist <= 20, using the EXACT rounded formula validated in R1:
//   cross = rn(rn(px*gx) + rn(py*gy))
//   d2    = rn(rn(p2 + g2) - rn(2*cross));  dist = sqrtf(max(d2, 0))
// Constant idempotent writes -> races between points are benign, no atomics.
// Box: 43x43 starting at floor(g)-21 covers [g-22, g+22] (rounding margin ok).
// ---------------------------------------------------------------------------
__global__ __launch_bounds__(256) void cover_kernel(
    const float* __restrict__ gt_points,   // (BS, GMAX, 2)
    const int*   __restrict__ gt_nums,     // (BS,)
    float*       __restrict__ out)
{
    const int b = blockIdx.y;
    const int g = blockIdx.x;
    if (g >= gt_nums[b]) return;

    const float gx = gt_points[(b * GMAX + g) * 2 + 0];
    const float gy = gt_points[(b * GMAX + g) * 2 + 1];
    const float g2 = __fadd_rn(__fmul_rn(gx, gx), __fmul_rn(gy, gy));

    const int x0 = (int)floorf(gx) - 21;
    const int y0 = (int)floorf(gy) - 21;

    for (int local = threadIdx.x; local < 43 * 43; local += 256) {
        const int lx = local / 43;
        const int ly = local - lx * 43;
        const int pxi = x0 + lx;
        const int pyi = y0 + ly;
        if ((unsigned)pxi > 255u || (unsigned)pyi > 255u) continue;
        const float px = (float)pxi;
        const float py = (float)pyi;
        const float p2 = px * px + py * py;            // exact (ints < 2^24)
        const float cross = __fadd_rn(__fmul_rn(px, gx), __fmul_rn(py, gy));
        const float d2 = __fsub_rn(__fadd_rn(p2, g2), __fmul_rn(2.0f, cross));
        const float dist = sqrtf(fmaxf(d2, 0.0f));
        if (dist <= DIS_THR)
            out[FLAG_OFF + b * HW + (pxi << 8) + pyi] = 0.0f;
    }
}

// ---------------------------------------------------------------------------
// Kernel C: positive scatter — flag[b, base+off] = 1.0 (unchanged from R1).
// ---------------------------------------------------------------------------
__global__ __launch_bounds__(128) void scatter_kernel(
    const float* __restrict__ gt_points,
    const int*   __restrict__ gt_nums,
    float*       __restrict__ out)
{
    const int b = blockIdx.y;
    const int g = blockIdx.x;
    if (g >= gt_nums[b]) return;

    const int k = threadIdx.x;
    if (k >= K_OFF) return;

    // ring index from cumulative sizes {8,16,24,32,40} -> starts {0,8,24,48,80}
    int i, start;
    if      (k < 8)  { i = 0; start = 0;  }
    else if (k < 24) { i = 1; start = 8;  }
    else if (k < 48) { i = 2; start = 24; }
    else if (k < 80) { i = 3; start = 48; }
    else             { i = 4; start = 80; }
    const int    j   = k - start;
    const int    nn  = 8 * (i + 1);
    const double r   = 4.0 * (i + 1);
    const double ang = ((double)j / (double)nn) * 6.283185307179586; // 2.0*np.pi
    const double dx  = r * cos(ang);
    const double dy  = r * sin(ang);
    const int off = (int)rint(dy * 256.0 + dx * 256.0);  // np.round, half-even

    const float gx = gt_points[(b * GMAX + g) * 2 + 0];
    const float gy = gt_points[(b * GMAX + g) * 2 + 1];
    // gx*256, gy*256 exact (power of 2); single rounded add; rintf = half-even
    const int base = (int)rintf(__fadd_rn(__fmul_rn(gx, 256.0f),
                                          __fmul_rn(gy, 256.0f)));
    const int idx = base + off;
    if (idx >= 0 && idx < HW)
        out[FLAG_OFF + b * HW + idx] = 1.0f;
}

extern "C" void kernel_launch(void* const* d_in, const int* in_sizes, int n_in,
                              void* d_out, int out_size, void* d_ws, size_t ws_size,
                              hipStream_t stream) {
    // inputs: [0] images (unused), [1] gt_points, [2] gt_nums
    const float* gt_points = (const float*)d_in[1];
    const int*   gt_nums   = (const int*)d_in[2];
    float* out = (float*)d_out;

    init_kernel<<<dim3(BS * HW / 256), 256, 0, stream>>>(out);

    cover_kernel<<<dim3(GMAX, BS), 256, 0, stream>>>(gt_points, gt_nums, out);

    scatter_kernel<<<dim3(GMAX, BS), 128, 0, stream>>>(gt_points, gt_nums, out);
}

// Round 3
// 14.060 us; speedup vs baseline: 5.4100x; 1.3167x over previous
//
#include <hip/hip_runtime.h>
#include <math.h>

// Problem constants (fixed by setup_inputs / module constants)
#define BS   4
#define GMAX 500
#define HW   65536           // 256*256
#define K_OFF 120            // 8*(1+2+3+4+5)
#define FLAG_OFF (BS * HW * 2)
#define DIS_THR 20.0f        // STRIDE*RADIUS
#define OFF_MAX 7241         // max |round(256*(dx+dy))| = round(256*20*sqrt(2))

struct OffsetsArg { int v[K_OFF]; };

// ---------------------------------------------------------------------------
// Single fused kernel. One block = one 16x16 pixel tile of one image.
//   phase 1: scan all GT points -> LDS lists
//            (a) disk candidates: coord box overlap +-22  (dist<=20 + margin)
//            (b) scatter candidates: base flat-index within +-OFF_MAX of tile
//   phase 2: per-pixel disk test (exact R1-validated rounding) +
//            scatter-mark pass into a 256-entry LDS tile mask
//   phase 3: store pixels (float2) and flag = mark ? 1 : (covered ? 0 : -1)
// ---------------------------------------------------------------------------
__global__ __launch_bounds__(256) void fused_kernel(
    const float* __restrict__ gt_points,   // (BS, GMAX, 2)
    const int*   __restrict__ gt_nums,     // (BS,)
    OffsetsArg offs,                       // 120 ring offsets (host-computed)
    float*       __restrict__ out)         // [BS*HW*2 pixels | BS*HW flag]
{
    const int b    = blockIdx.z;
    const int tx0  = blockIdx.x << 4;           // tile origin px
    const int ty0  = blockIdx.y << 4;           // tile origin py
    const int nmin = (tx0 << 8) + ty0;          // smallest flat index in tile

    __shared__ float sgx[GMAX], sgy[GMAX], sg2[GMAX];
    __shared__ int   sbase[GMAX];
    __shared__ int   offl[K_OFF];
    __shared__ unsigned char smark[256];
    __shared__ int   dcnt_, scnt_;

    const int tid = threadIdx.x;
    if (tid == 0) { dcnt_ = 0; scnt_ = 0; }
    smark[tid] = 0;
    if (tid < K_OFF) offl[tid] = offs.v[tid];
    __syncthreads();

    const int num = gt_nums[b];
    const float xlo = (float)(tx0 - 22), xhi = (float)(tx0 + 15 + 22);
    const float ylo = (float)(ty0 - 22), yhi = (float)(ty0 + 15 + 22);
    const int   blo = nmin - OFF_MAX,    bhi = nmin + 3855 + OFF_MAX;

    for (int g = tid; g < num; g += 256) {
        const float2 gp = ((const float2*)gt_points)[b * GMAX + g];
        const float gx = gp.x, gy = gp.y;
        // disk candidate: could any tile pixel be within dist 20 (+rounding)?
        if (gx >= xlo && gx <= xhi && gy >= ylo && gy <= yhi) {
            const int s = atomicAdd(&dcnt_, 1);
            sgx[s] = gx; sgy[s] = gy;
            sg2[s] = __fadd_rn(__fmul_rn(gx, gx), __fmul_rn(gy, gy));
        }
        // scatter candidate: base + off could land in this tile's flat range
        // (same rintf formula as validated scatter: products by 256 exact,
        //  one rounded add, half-even rint == jnp.round)
        const int base = (int)rintf(__fadd_rn(__fmul_rn(gx, 256.0f),
                                              __fmul_rn(gy, 256.0f)));
        if (base >= blo && base <= bhi) {
            const int s = atomicAdd(&scnt_, 1);
            sbase[s] = base;
        }
    }
    __syncthreads();

    // --- per-pixel disk coverage (exact rounded formula from R1/R2) ---
    const int lx = tid >> 4, ly = tid & 15;
    const int pxi = tx0 + lx, pyi = ty0 + ly;
    const float px = (float)pxi, py = (float)pyi;
    const float p2 = px * px + py * py;          // exact (ints < 2^24)

    bool found = false;
    const int dcnt = dcnt_;
    for (int i = 0; i < dcnt; ++i) {
        const float cross = __fadd_rn(__fmul_rn(px, sgx[i]),
                                      __fmul_rn(py, sgy[i]));
        const float d2 = __fsub_rn(__fadd_rn(p2, sg2[i]),
                                   __fmul_rn(2.0f, cross));
        found |= (sqrtf(fmaxf(d2, 0.0f)) <= DIS_THR);
    }

    // --- scatter-mark pass: candidates x 120 offsets -> LDS tile mask ---
    // idx = base + off; in-tile iff (idx-nmin) in [0,3855] and column < 16.
    // Races write the constant 1 -> benign. Tile flats are all in [0,HW).
    const int total = scnt_ * K_OFF;
    for (int p = tid; p < total; p += 256) {
        const int s = p / K_OFF;                 // magic-mul division
        const int k = p - s * K_OFF;
        const unsigned local = (unsigned)(sbase[s] + offl[k] - nmin);
        if (local <= 3855u && (local & 255u) < 16u)
            smark[((local >> 8) << 4) | (local & 15u)] = 1;
    }
    __syncthreads();

    // --- final stores: priority scatter(+1) > covered(0) > negative(-1) ---
    const int n = (pxi << 8) | pyi;
    ((float2*)out)[b * HW + n] = make_float2(px, py);
    out[FLAG_OFF + b * HW + n] = smark[tid] ? 1.0f : (found ? 0.0f : -1.0f);
}

extern "C" void kernel_launch(void* const* d_in, const int* in_sizes, int n_in,
                              void* d_out, int out_size, void* d_ws, size_t ws_size,
                              hipStream_t stream) {
    // inputs: [0] images (unused), [1] gt_points, [2] gt_nums
    const float* gt_points = (const float*)d_in[1];
    const int*   gt_nums   = (const int*)d_in[2];
    float* out = (float*)d_out;

    // Ring offsets: host double trig (libm = what numpy uses), half-even rint.
    // Deterministic pure function of constants -> safe to recompute per call.
    OffsetsArg offs;
    {
        int k = 0;
        for (int i = 0; i < 5; ++i) {
            const int    nn = 8 * (i + 1);
            const double r  = 4.0 * (i + 1);
            for (int j = 0; j < nn; ++j) {
                const double ang = (double)j / (double)nn * 2.0 * M_PI;
                const double dx  = r * cos(ang);
                const double dy  = r * sin(ang);
                offs.v[k++] = (int)rint(dy * 256.0 + dx * 256.0);
            }
        }
    }

    fused_kernel<<<dim3(16, 16, BS), 256, 0, stream>>>(gt_points, gt_nums, offs, out);
}